// Round 10
// baseline (263.492 us; speedup 1.0000x reference)
//
#include <hip/hip_runtime.h>
#include <math.h>

#define BB 16
#define LC 1024
#define LQ 1024
#define DD 256

#define CTB 64     // c rows per block (k_main)
#define QTB 64     // q rows per tile
#define QT_S 72    // k_prep LDS transpose stride (144 B)

typedef __attribute__((ext_vector_type(4))) float f32x4;
typedef __attribute__((ext_vector_type(8))) short bf16x8;
typedef __attribute__((ext_vector_type(4))) short bf16x4;

__device__ inline short f2bf(float f) {
    union { float f; unsigned u; } v; v.f = f;
    unsigned r = v.u + 0x7FFFu + ((v.u >> 16) & 1u);   // RNE
    return (short)(r >> 16);
}

// ws layout (floats):
// [0, 16384)        qterm[b][q]   (written by k_prep)
// [32768, 49152)    rowmax[b][c]  (written by k_main; includes cterm)
// [49152, 53248)    q2cvec[b][d]  (zeroed by k_prep)
// Qbf/Qtbf bf16 panels live in the q2c half of d_out (overwritten by k_bcast last).

__global__ __launch_bounds__(256) void k_prep(const float* __restrict__ qst,
                                              const float* __restrict__ w,
                                              short* __restrict__ Qbf,
                                              short* __restrict__ Qtbf,
                                              float* __restrict__ qterm,
                                              float* __restrict__ q2cvec) {
    __shared__ short Qt_lds[DD][QT_S];
    int t = threadIdx.x;
    int qt = blockIdx.x;
    int b  = blockIdx.y;
    int wv4 = t >> 6;
    int l   = t & 63;
    int lx  = l & 15;
    int ls  = l >> 4;

    if (qt == 0) q2cvec[b * DD + t] = 0.f;   // replaces the hipMemsetAsync launch

    #pragma unroll
    for (int kq = 0; kq < 4; ++kq) {
        int ql = 16 * wv4 + 4 * kq + ls;
        float qpart = 0.f;
        #pragma unroll
        for (int jd = 0; jd < 4; ++jd) {
            int d0 = 64 * jd + 4 * lx;
            float4 x = *(const float4*)(qst + ((size_t)(b * LQ + qt * QTB + ql)) * DD + d0);
            float4 wq = *(const float4*)(w + DD + d0);
            qpart += x.x * wq.x + x.y * wq.y + x.z * wq.z + x.w * wq.w;
            bf16x4 o;
            o[0] = f2bf(x.x); o[1] = f2bf(x.y); o[2] = f2bf(x.z); o[3] = f2bf(x.w);
            *(bf16x4*)(Qbf + ((size_t)(b * LQ + qt * QTB + ql)) * DD + d0) = o;
            // 4x4 transpose among lanes {lx, lx+16, lx+32, lx+48}
            float X[4] = {x.x, x.y, x.z, x.w};
            float P1[4], X1[4], P2[4], X2[4];
            #pragma unroll
            for (int e = 0; e < 4; ++e) P1[e] = __shfl_xor(X[e ^ 1], 16);
            #pragma unroll
            for (int e = 0; e < 4; ++e) X1[e] = ((ls & 1) == (e & 1)) ? X[e] : P1[e];
            #pragma unroll
            for (int e = 0; e < 4; ++e) P2[e] = __shfl_xor(X1[e ^ 2], 32);
            #pragma unroll
            for (int e = 0; e < 4; ++e) X2[e] = ((ls & 2) == (e & 2)) ? X1[e] : P2[e];
            int dl = 64 * jd + 4 * lx + ls;
            bf16x4 ot;
            ot[0] = f2bf(X2[0]); ot[1] = f2bf(X2[1]); ot[2] = f2bf(X2[2]); ot[3] = f2bf(X2[3]);
            *(bf16x4*)&Qt_lds[dl][16 * wv4 + 4 * kq] = ot;
        }
        qpart += __shfl_xor(qpart, 1);
        qpart += __shfl_xor(qpart, 2);
        qpart += __shfl_xor(qpart, 4);
        qpart += __shfl_xor(qpart, 8);
        if (lx == 0) qterm[b * LQ + qt * QTB + ql] = qpart;
    }
    __syncthreads();
    #pragma unroll
    for (int rep = 0; rep < 8; ++rep) {
        int d   = rep * 32 + (t >> 3);
        int qch = t & 7;
        bf16x8 v = *(const bf16x8*)&Qt_lds[d][8 * qch];
        *(bf16x8*)(Qtbf + ((size_t)(b * DD + d)) * LQ + qt * QTB + 8 * qch) = v;
    }
}

// Main flash kernel: 1024 threads = 16 waves = 4 q-groups x 4 waves.
// Group g handles q-tiles (4*it + g), it = 0..3; 4-way merged in-block at the end.
// 1-D grid, b = bid & 15 so all blocks of a batch share an XCD (bid%8 == b%8).
__global__ __launch_bounds__(1024) void k_main(const float* __restrict__ ctx,
                                               const short* __restrict__ Qbf,
                                               const short* __restrict__ Qtbf,
                                               const float* __restrict__ wght,
                                               const float* __restrict__ ws,
                                               float* __restrict__ out,
                                               float* __restrict__ rowmax_out) {
    // LDS pool: CMp (32 KB) | sPp (32 KB, overlaid by mergebuf 69.6 KB after the loop)
    __shared__ __align__(16) char pool[32768 + 256 * 68 * 4];
    short* CMp = (short*)pool;                       // [4 strips][8 kk][512 lanes][8]
    short* sPp = (short*)(pool + 32768);             // [4 groups][4096]
    float* mergebuf = (float*)(pool + 32768);        // [256 slots][68] (17x16B: conflict-free)
    __shared__ float scaleS[4][CTB];
    __shared__ float mS[4][CTB], lS[4][CTB];
    __shared__ float ctermS[2][CTB];

    const int t  = threadIdx.x;
    const int wv = t >> 6;          // 0..15
    const int g  = wv >> 2;         // q-group 0..3
    const int w4 = wv & 3;          // c-strip (S) / d-slice (PV)
    const int l  = t & 63;
    const int lx = l & 15;
    const int ls = l >> 4;
    const int bid = blockIdx.x;
    const int b  = bid & 15;
    const int c0 = (bid >> 4) * CTB;

    const float* qterm = ws;

    // ---- stage CM packed + cterm partial: waves with g<2 stage strip w4, kk-half g
    if (g < 2) {
        const int kh = g * 4;
        int cl = 16 * w4 + lx;
        float cpart = 0.f;
        #pragma unroll
        for (int kq = 0; kq < 4; ++kq) {
            int kk = kh + kq;
            int d0 = 32 * kk + 8 * ls;
            const float4 x0 = *(const float4*)(ctx + ((size_t)(b * LC + c0 + cl)) * DD + d0);
            const float4 x1 = *(const float4*)(ctx + ((size_t)(b * LC + c0 + cl)) * DD + d0 + 4);
            const float4 w0 = *(const float4*)(wght + 2 * DD + d0);
            const float4 w1 = *(const float4*)(wght + 2 * DD + d0 + 4);
            const float4 c0v = *(const float4*)(wght + d0);
            const float4 c1v = *(const float4*)(wght + d0 + 4);
            cpart += x0.x * c0v.x + x0.y * c0v.y + x0.z * c0v.z + x0.w * c0v.w
                   + x1.x * c1v.x + x1.y * c1v.y + x1.z * c1v.z + x1.w * c1v.w;
            bf16x8 o;
            o[0] = f2bf(x0.x * w0.x); o[1] = f2bf(x0.y * w0.y);
            o[2] = f2bf(x0.z * w0.z); o[3] = f2bf(x0.w * w0.w);
            o[4] = f2bf(x1.x * w1.x); o[5] = f2bf(x1.y * w1.y);
            o[6] = f2bf(x1.z * w1.z); o[7] = f2bf(x1.w * w1.w);
            *(bf16x8*)&CMp[(w4 * 8 + kk) * 512 + l * 8] = o;
        }
        cpart += __shfl_xor(cpart, 16);
        cpart += __shfl_xor(cpart, 32);
        if (ls == 0) ctermS[g][cl] = cpart;
    }

    float mrun[4], lrun[4];
    f32x4 oacc[4][4];               // [cf][df], rows c=16cf+4ls+r, cols d=64*w4+16df+lx
    #pragma unroll
    for (int r = 0; r < 4; ++r) { mrun[r] = -1e30f; lrun[r] = 0.f; }
    #pragma unroll
    for (int cf = 0; cf < 4; ++cf)
        #pragma unroll
        for (int df = 0; df < 4; ++df)
            oacc[cf][df] = (f32x4){0.f, 0.f, 0.f, 0.f};

    __syncthreads();   // CMp + ctermS ready

    for (int it = 0; it < 4; ++it) {
        const int qtile = 4 * it + g;
        const size_t qbase = (size_t)b * LQ + qtile * QTB;

        // ---- S = CM @ Q^T
        f32x4 sacc[4];
        #pragma unroll
        for (int f = 0; f < 4; ++f) sacc[f] = (f32x4){0.f, 0.f, 0.f, 0.f};
        bf16x8 bA[4][4], bB[4][4];
        #pragma unroll
        for (int kk = 0; kk < 4; ++kk)
            #pragma unroll
            for (int f = 0; f < 4; ++f)
                bA[kk][f] = *(const bf16x8*)(Qbf + (qbase + 16 * f + lx) * DD + 32 * kk + 8 * ls);
        bf16x8 acur = *(const bf16x8*)&CMp[(w4 * 8 + 0) * 512 + l * 8];
        #pragma unroll
        for (int kk = 0; kk < 4; ++kk) {
            bf16x8 anext = *(const bf16x8*)&CMp[(w4 * 8 + kk + 1) * 512 + l * 8];
            #pragma unroll
            for (int f = 0; f < 4; ++f)
                bB[kk][f] = *(const bf16x8*)(Qbf + (qbase + 16 * f + lx) * DD + 32 * (kk + 4) + 8 * ls);
            #pragma unroll
            for (int f = 0; f < 4; ++f)
                sacc[f] = __builtin_amdgcn_mfma_f32_16x16x32_bf16(acur, bA[kk][f], sacc[f], 0, 0, 0);
            acur = anext;
        }
        #pragma unroll
        for (int kk = 4; kk < 8; ++kk) {
            bf16x8 anext = (kk < 7) ? *(const bf16x8*)&CMp[(w4 * 8 + kk + 1) * 512 + l * 8] : acur;
            #pragma unroll
            for (int f = 0; f < 4; ++f)
                sacc[f] = __builtin_amdgcn_mfma_f32_16x16x32_bf16(acur, bB[kk - 4][f], sacc[f], 0, 0, 0);
            acur = anext;
        }

        // ---- hoist PV B-operand loads (hidden under softmax VALU)
        bf16x8 qtb[2][4];
        #pragma unroll
        for (int kk = 0; kk < 2; ++kk)
            #pragma unroll
            for (int df = 0; df < 4; ++df)
                qtb[kk][df] = *(const bf16x8*)(Qtbf + ((size_t)(b * DD + 64 * w4 + 16 * df + lx)) * LQ
                                               + qtile * QTB + 32 * kk + 8 * ls);

        // ---- qterm + online softmax
        float qv[4];
        #pragma unroll
        for (int f = 0; f < 4; ++f) qv[f] = qterm[qbase + 16 * f + lx];
        #pragma unroll
        for (int f = 0; f < 4; ++f) {
            #pragma unroll
            for (int r = 0; r < 4; ++r) sacc[f][r] += qv[f];
        }
        float scl[4];
        #pragma unroll
        for (int r = 0; r < 4; ++r) {
            float v = fmaxf(fmaxf(sacc[0][r], sacc[1][r]), fmaxf(sacc[2][r], sacc[3][r]));
            v = fmaxf(v, __shfl_xor(v, 1));
            v = fmaxf(v, __shfl_xor(v, 2));
            v = fmaxf(v, __shfl_xor(v, 4));
            v = fmaxf(v, __shfl_xor(v, 8));
            float mn = fmaxf(mrun[r], v);
            scl[r] = __expf(mrun[r] - mn);
            mrun[r] = mn;
            lrun[r] *= scl[r];
        }
        float p[4][4];
        float rs[4] = {0.f, 0.f, 0.f, 0.f};
        #pragma unroll
        for (int f = 0; f < 4; ++f)
            #pragma unroll
            for (int r = 0; r < 4; ++r) {
                p[f][r] = __expf(sacc[f][r] - mrun[r]);
                rs[r] += p[f][r];
            }
        #pragma unroll
        for (int r = 0; r < 4; ++r) {
            float v = rs[r];
            v += __shfl_xor(v, 1);
            v += __shfl_xor(v, 2);
            v += __shfl_xor(v, 4);
            v += __shfl_xor(v, 8);
            lrun[r] += v;
        }
        // ---- write P into packed frag layout
        #pragma unroll
        for (int f = 0; f < 4; ++f) {
            #pragma unroll
            for (int r = 0; r < 4; ++r) {
                int cl = 16 * w4 + 4 * ls + r;
                int ql = 16 * f + lx;
                int idx = ((cl >> 4) * 2 + (ql >> 5)) * 512 + ((cl & 15) + 16 * ((ql >> 3) & 3)) * 8 + (ql & 7);
                sPp[g * 4096 + idx] = f2bf(p[f][r]);
            }
        }
        if (lx == 0) {
            #pragma unroll
            for (int r = 0; r < 4; ++r) scaleS[g][16 * w4 + 4 * ls + r] = scl[r];
        }
        __syncthreads();   // sP + scales ready

        // ---- PV: wave owns d-slice [64*w4, +64), all 64 c of its group
        #pragma unroll
        for (int cf = 0; cf < 4; ++cf) {
            #pragma unroll
            for (int r = 0; r < 4; ++r) {
                float s = scaleS[g][16 * cf + 4 * ls + r];
                #pragma unroll
                for (int df = 0; df < 4; ++df) oacc[cf][df][r] *= s;
            }
        }
        bf16x8 pa[2][4];
        #pragma unroll
        for (int kk = 0; kk < 2; ++kk)
            #pragma unroll
            for (int cf = 0; cf < 4; ++cf)
                pa[kk][cf] = *(const bf16x8*)&sPp[g * 4096 + (cf * 2 + kk) * 512 + l * 8];
        #pragma unroll
        for (int kk = 0; kk < 2; ++kk)
            #pragma unroll
            for (int df = 0; df < 4; ++df)
                #pragma unroll
                for (int cf = 0; cf < 4; ++cf)
                    oacc[cf][df] = __builtin_amdgcn_mfma_f32_16x16x32_bf16(pa[kk][cf], qtb[kk][df], oacc[cf][df], 0, 0, 0);
        __syncthreads();   // PV done; next iter (or merge) may overwrite sPp
    }

    // ---- in-block 4-way merge
    if (lx == 0) {
        #pragma unroll
        for (int r = 0; r < 4; ++r) {
            mS[g][16 * w4 + 4 * ls + r] = mrun[r];
            lS[g][16 * w4 + 4 * ls + r] = lrun[r];
        }
    }
    __syncthreads();

    float alpha[4][4], ltot[4][4], mtot[4][4];   // [cf][r]
    #pragma unroll
    for (int cf = 0; cf < 4; ++cf) {
        #pragma unroll
        for (int r = 0; r < 4; ++r) {
            int cl = 16 * cf + 4 * ls + r;
            float mx = fmaxf(fmaxf(mS[0][cl], mS[1][cl]), fmaxf(mS[2][cl], mS[3][cl]));
            float lt = 0.f;
            #pragma unroll
            for (int j = 0; j < 4; ++j) lt += __expf(mS[j][cl] - mx) * lS[j][cl];
            mtot[cf][r] = mx;
            ltot[cf][r] = lt;
            alpha[cf][r] = __expf(mS[g][cl] - mx);
        }
    }
    #pragma unroll
    for (int cf = 0; cf < 4; ++cf)
        #pragma unroll
        for (int df = 0; df < 4; ++df)
            #pragma unroll
            for (int r = 0; r < 4; ++r)
                oacc[cf][df][r] *= alpha[cf][r];

    const int slot = (w4 * 64 + l) * 68;
    for (int src = 1; src < 4; ++src) {
        if (g == src) {
            #pragma unroll
            for (int cf = 0; cf < 4; ++cf)
                #pragma unroll
                for (int df = 0; df < 4; ++df)
                    *(f32x4*)&mergebuf[slot + (cf * 4 + df) * 4] = oacc[cf][df];
        }
        __syncthreads();
        if (g == 0) {
            #pragma unroll
            for (int cf = 0; cf < 4; ++cf)
                #pragma unroll
                for (int df = 0; df < 4; ++df) {
                    f32x4 v = *(const f32x4*)&mergebuf[slot + (cf * 4 + df) * 4];
                    oacc[cf][df][0] += v[0]; oacc[cf][df][1] += v[1];
                    oacc[cf][df][2] += v[2]; oacc[cf][df][3] += v[3];
                }
        }
        __syncthreads();
    }

    if (g == 0) {
        if (wv == 0 && lx == 0) {
            #pragma unroll
            for (int cf = 0; cf < 4; ++cf)
                #pragma unroll
                for (int r = 0; r < 4; ++r) {
                    int cl = 16 * cf + 4 * ls + r;
                    int c = b * LC + c0 + cl;
                    rowmax_out[c] = mtot[cf][r] + ctermS[0][cl] + ctermS[1][cl];
                }
        }
        #pragma unroll
        for (int cf = 0; cf < 4; ++cf) {
            #pragma unroll
            for (int r = 0; r < 4; ++r) {
                float inv = 1.0f / ltot[cf][r];
                size_t row = (size_t)(b * LC + c0 + 16 * cf + 4 * ls + r) * DD;
                #pragma unroll
                for (int df = 0; df < 4; ++df)
                    out[row + 64 * w4 + 16 * df + lx] = oacc[cf][df][r] * inv;
            }
        }
    }
}

__global__ __launch_bounds__(256) void k_q2c(const float* __restrict__ ctx,
                                             const float* __restrict__ rowmax,
                                             float* __restrict__ q2cvec) {
    __shared__ float sm[LC];
    __shared__ float red[256];
    int b = blockIdx.x;
    int chunk = blockIdx.y;
    int t = threadIdx.x;
    const float* rm = rowmax + b * LC;

    float lmax = -1e30f;
    #pragma unroll
    for (int k = 0; k < 4; ++k) {
        float v = rm[t + k * 256];
        sm[t + k * 256] = v;
        lmax = fmaxf(lmax, v);
    }
    red[t] = lmax;
    __syncthreads();
    for (int s = 128; s > 0; s >>= 1) {
        if (t < s) red[t] = fmaxf(red[t], red[t + s]);
        __syncthreads();
    }
    float gmax = red[0];
    __syncthreads();
    float lsum = 0.f;
    #pragma unroll
    for (int k = 0; k < 4; ++k) {
        int i = t + k * 256;
        float e = __expf(sm[i] - gmax);
        sm[i] = e;
        lsum += e;
    }
    red[t] = lsum;
    __syncthreads();
    for (int s = 128; s > 0; s >>= 1) {
        if (t < s) red[t] += red[t + s];
        __syncthreads();
    }
    float inv = 1.0f / red[0];

    int c0 = chunk * 32;
    float acc = 0.f;
    for (int c = c0; c < c0 + 32; ++c)
        acc += sm[c] * ctx[(size_t)(b * LC + c) * DD + t];
    atomicAdd(&q2cvec[b * DD + t], acc * inv);
}

__global__ __launch_bounds__(256) void k_bcast(const float* __restrict__ q2cvec,
                                               float* __restrict__ out2) {
    int g = blockIdx.x * 256 + threadIdx.x;
    int b  = g >> 16;
    int d4 = g & 63;
    ((float4*)out2)[g] = ((const float4*)q2cvec)[b * 64 + d4];
}

extern "C" void kernel_launch(void* const* d_in, const int* in_sizes, int n_in,
                              void* d_out, int out_size, void* d_ws, size_t ws_size,
                              hipStream_t stream) {
    const float* ctx = (const float*)d_in[0];
    const float* qst = (const float*)d_in[1];
    const float* w   = (const float*)d_in[2];
    float* out  = (float*)d_out;
    float* out2 = out + (size_t)BB * LC * DD;   // q2c half; bf16 scratch until k_bcast
    float* ws   = (float*)d_ws;

    float* qterm  = ws;
    float* rowmax = ws + 32768;
    float* q2cvec = ws + 49152;
    short* Qbf  = (short*)out2;
    short* Qtbf = Qbf + (size_t)BB * LQ * DD;

    k_prep<<<dim3(LQ / QTB, BB), 256, 0, stream>>>(qst, w, Qbf, Qtbf, qterm, q2cvec);

    k_main<<<(LC / CTB) * BB, 1024, 0, stream>>>(ctx, Qbf, Qtbf, w, ws, out, rowmax);

    k_q2c<<<dim3(BB, 32), 256, 0, stream>>>(ctx, rowmax, q2cvec);

    k_bcast<<<(BB * LC * DD / 4) / 256, 256, 0, stream>>>(q2cvec, out2);
}

// Round 11
// 183.976 us; speedup vs baseline: 1.4322x; 1.4322x over previous
//
#include <hip/hip_runtime.h>
#include <math.h>

#define BB 16
#define LC 1024
#define LQ 1024
#define DD 256

#define CTB 64     // c rows per block (k_main)
#define QTB 64     // q rows per tile
#define QT_S 72    // k_prep LDS transpose stride (144 B)

typedef __attribute__((ext_vector_type(4))) float f32x4;
typedef __attribute__((ext_vector_type(8))) short bf16x8;
typedef __attribute__((ext_vector_type(4))) short bf16x4;

__device__ inline short f2bf(float f) {
    union { float f; unsigned u; } v; v.f = f;
    unsigned r = v.u + 0x7FFFu + ((v.u >> 16) & 1u);   // RNE
    return (short)(r >> 16);
}

// ws layout (floats):
// [0, 16384)        qterm[b][q]   (written by k_prep)
// [32768, 49152)    rowmax[b][c]  (written by k_main; includes cterm)
// [49152, 53248)    q2cvec[b][d]  (zeroed by k_prep)
// Qbf/Qtbf bf16 panels live in the q2c half of d_out (overwritten by k_bcast last).

__global__ __launch_bounds__(256) void k_prep(const float* __restrict__ qst,
                                              const float* __restrict__ w,
                                              short* __restrict__ Qbf,
                                              short* __restrict__ Qtbf,
                                              float* __restrict__ qterm,
                                              float* __restrict__ q2cvec) {
    __shared__ short Qt_lds[DD][QT_S];
    int t = threadIdx.x;
    int qt = blockIdx.x;
    int b  = blockIdx.y;
    int wv4 = t >> 6;
    int l   = t & 63;
    int lx  = l & 15;
    int ls  = l >> 4;

    if (qt == 0) q2cvec[b * DD + t] = 0.f;   // replaces the hipMemsetAsync launch

    #pragma unroll
    for (int kq = 0; kq < 4; ++kq) {
        int ql = 16 * wv4 + 4 * kq + ls;
        float qpart = 0.f;
        #pragma unroll
        for (int jd = 0; jd < 4; ++jd) {
            int d0 = 64 * jd + 4 * lx;
            float4 x = *(const float4*)(qst + ((size_t)(b * LQ + qt * QTB + ql)) * DD + d0);
            float4 wq = *(const float4*)(w + DD + d0);
            qpart += x.x * wq.x + x.y * wq.y + x.z * wq.z + x.w * wq.w;
            bf16x4 o;
            o[0] = f2bf(x.x); o[1] = f2bf(x.y); o[2] = f2bf(x.z); o[3] = f2bf(x.w);
            *(bf16x4*)(Qbf + ((size_t)(b * LQ + qt * QTB + ql)) * DD + d0) = o;
            // 4x4 transpose among lanes {lx, lx+16, lx+32, lx+48}
            float X[4] = {x.x, x.y, x.z, x.w};
            float P1[4], X1[4], P2[4], X2[4];
            #pragma unroll
            for (int e = 0; e < 4; ++e) P1[e] = __shfl_xor(X[e ^ 1], 16);
            #pragma unroll
            for (int e = 0; e < 4; ++e) X1[e] = ((ls & 1) == (e & 1)) ? X[e] : P1[e];
            #pragma unroll
            for (int e = 0; e < 4; ++e) P2[e] = __shfl_xor(X1[e ^ 2], 32);
            #pragma unroll
            for (int e = 0; e < 4; ++e) X2[e] = ((ls & 2) == (e & 2)) ? X1[e] : P2[e];
            int dl = 64 * jd + 4 * lx + ls;
            bf16x4 ot;
            ot[0] = f2bf(X2[0]); ot[1] = f2bf(X2[1]); ot[2] = f2bf(X2[2]); ot[3] = f2bf(X2[3]);
            *(bf16x4*)&Qt_lds[dl][16 * wv4 + 4 * kq] = ot;
        }
        qpart += __shfl_xor(qpart, 1);
        qpart += __shfl_xor(qpart, 2);
        qpart += __shfl_xor(qpart, 4);
        qpart += __shfl_xor(qpart, 8);
        if (lx == 0) qterm[b * LQ + qt * QTB + ql] = qpart;
    }
    __syncthreads();
    #pragma unroll
    for (int rep = 0; rep < 8; ++rep) {
        int d   = rep * 32 + (t >> 3);
        int qch = t & 7;
        bf16x8 v = *(const bf16x8*)&Qt_lds[d][8 * qch];
        *(bf16x8*)(Qtbf + ((size_t)(b * DD + d)) * LQ + qt * QTB + 8 * qch) = v;
    }
}

// Main flash kernel: 512 threads = 8 waves = 2 q-groups x 4 waves.
// Group g handles q-tiles (2*it + g), it = 0..7; merged in-block at the end.
// 1-D grid, b = bid & 15 so all blocks of a batch share an XCD (bid%8 == b%8).
// __launch_bounds__(512, 2): min 2 waves/EU -> VGPR cap 256, so the depth-4
// B prefetch (bA/bB = 128 VGPRs) can actually stay in registers (v4 had 96
// VGPRs and the compiler sank the prefetch; v5's 1024-thr forced 64 + spill).
__global__ __launch_bounds__(512, 2) void k_main(const float* __restrict__ ctx,
                                                 const short* __restrict__ Qbf,
                                                 const short* __restrict__ Qtbf,
                                                 const float* __restrict__ wght,
                                                 const float* __restrict__ ws,
                                                 float* __restrict__ out,
                                                 float* __restrict__ rowmax_out) {
    __shared__ short CMp[4 * 8 * 512];          // packed A-frags: [w4][kk][lane][8], 32 KB
    __shared__ short sPp[2][4 * 2 * 512];       // packed P-frags per group, 16 KB
    __shared__ float scaleS[2][CTB];
    __shared__ float mS[2][CTB], lS[2][CTB];
    __shared__ float ctermS[2][CTB];
    __shared__ float mergebuf[4 * 64 * 20];     // stride 20 f32 -> conflict-free f32x4

    const int t  = threadIdx.x;
    const int wv = t >> 6;          // 0..7
    const int g  = wv >> 2;         // q-group
    const int w4 = wv & 3;          // c-strip (S) / d-slice (PV)
    const int l  = t & 63;
    const int lx = l & 15;
    const int ls = l >> 4;
    const int bid = blockIdx.x;
    const int b  = bid & 15;
    const int c0 = (bid >> 4) * CTB;

    const float* qterm = ws;

    // ---- stage CM packed + cterm partial: wave (g,w4) stages strip w4, kk-half g
    {
        const int kh = g * 4;
        int cl = 16 * w4 + lx;
        float cpart = 0.f;
        #pragma unroll
        for (int kq = 0; kq < 4; ++kq) {
            int kk = kh + kq;
            int d0 = 32 * kk + 8 * ls;
            const float4 x0 = *(const float4*)(ctx + ((size_t)(b * LC + c0 + cl)) * DD + d0);
            const float4 x1 = *(const float4*)(ctx + ((size_t)(b * LC + c0 + cl)) * DD + d0 + 4);
            const float4 w0 = *(const float4*)(wght + 2 * DD + d0);
            const float4 w1 = *(const float4*)(wght + 2 * DD + d0 + 4);
            const float4 c0v = *(const float4*)(wght + d0);
            const float4 c1v = *(const float4*)(wght + d0 + 4);
            cpart += x0.x * c0v.x + x0.y * c0v.y + x0.z * c0v.z + x0.w * c0v.w
                   + x1.x * c1v.x + x1.y * c1v.y + x1.z * c1v.z + x1.w * c1v.w;
            bf16x8 o;
            o[0] = f2bf(x0.x * w0.x); o[1] = f2bf(x0.y * w0.y);
            o[2] = f2bf(x0.z * w0.z); o[3] = f2bf(x0.w * w0.w);
            o[4] = f2bf(x1.x * w1.x); o[5] = f2bf(x1.y * w1.y);
            o[6] = f2bf(x1.z * w1.z); o[7] = f2bf(x1.w * w1.w);
            *(bf16x8*)&CMp[(w4 * 8 + kk) * 512 + l * 8] = o;
        }
        cpart += __shfl_xor(cpart, 16);
        cpart += __shfl_xor(cpart, 32);
        if (ls == 0) ctermS[g][cl] = cpart;
    }

    float mrun[4], lrun[4];
    f32x4 oacc[4][4];               // [cf][df], rows c=16cf+4ls+r, cols d=64*w4+16df+lx
    #pragma unroll
    for (int r = 0; r < 4; ++r) { mrun[r] = -1e30f; lrun[r] = 0.f; }
    #pragma unroll
    for (int cf = 0; cf < 4; ++cf)
        #pragma unroll
        for (int df = 0; df < 4; ++df)
            oacc[cf][df] = (f32x4){0.f, 0.f, 0.f, 0.f};

    __syncthreads();   // CMp + ctermS ready

    for (int it = 0; it < 8; ++it) {
        const int qtile = 2 * it + g;
        const size_t qbase = (size_t)b * LQ + qtile * QTB;

        // ---- S = CM @ Q^T, depth-4 B prefetch, 1-deep A prefetch (all static)
        f32x4 sacc[4];
        #pragma unroll
        for (int f = 0; f < 4; ++f) sacc[f] = (f32x4){0.f, 0.f, 0.f, 0.f};
        bf16x8 bA[4][4], bB[4][4];
        #pragma unroll
        for (int kk = 0; kk < 4; ++kk)
            #pragma unroll
            for (int f = 0; f < 4; ++f)
                bA[kk][f] = *(const bf16x8*)(Qbf + (qbase + 16 * f + lx) * DD + 32 * kk + 8 * ls);
        bf16x8 acur = *(const bf16x8*)&CMp[(w4 * 8 + 0) * 512 + l * 8];
        #pragma unroll
        for (int kk = 0; kk < 4; ++kk) {
            bf16x8 anext = *(const bf16x8*)&CMp[(w4 * 8 + kk + 1) * 512 + l * 8];
            #pragma unroll
            for (int f = 0; f < 4; ++f)
                bB[kk][f] = *(const bf16x8*)(Qbf + (qbase + 16 * f + lx) * DD + 32 * (kk + 4) + 8 * ls);
            #pragma unroll
            for (int f = 0; f < 4; ++f)
                sacc[f] = __builtin_amdgcn_mfma_f32_16x16x32_bf16(acur, bA[kk][f], sacc[f], 0, 0, 0);
            acur = anext;
        }
        #pragma unroll
        for (int kk = 4; kk < 8; ++kk) {
            bf16x8 anext = (kk < 7) ? *(const bf16x8*)&CMp[(w4 * 8 + kk + 1) * 512 + l * 8] : acur;
            #pragma unroll
            for (int f = 0; f < 4; ++f)
                sacc[f] = __builtin_amdgcn_mfma_f32_16x16x32_bf16(acur, bB[kk - 4][f], sacc[f], 0, 0, 0);
            acur = anext;
        }

        // ---- hoist PV B-operand loads (hidden under softmax VALU)
        bf16x8 qtb[2][4];
        #pragma unroll
        for (int kk = 0; kk < 2; ++kk)
            #pragma unroll
            for (int df = 0; df < 4; ++df)
                qtb[kk][df] = *(const bf16x8*)(Qtbf + ((size_t)(b * DD + 64 * w4 + 16 * df + lx)) * LQ
                                               + qtile * QTB + 32 * kk + 8 * ls);

        // ---- qterm + online softmax
        float qv[4];
        #pragma unroll
        for (int f = 0; f < 4; ++f) qv[f] = qterm[qbase + 16 * f + lx];
        #pragma unroll
        for (int f = 0; f < 4; ++f) {
            #pragma unroll
            for (int r = 0; r < 4; ++r) sacc[f][r] += qv[f];
        }
        float scl[4];
        #pragma unroll
        for (int r = 0; r < 4; ++r) {
            float v = fmaxf(fmaxf(sacc[0][r], sacc[1][r]), fmaxf(sacc[2][r], sacc[3][r]));
            v = fmaxf(v, __shfl_xor(v, 1));
            v = fmaxf(v, __shfl_xor(v, 2));
            v = fmaxf(v, __shfl_xor(v, 4));
            v = fmaxf(v, __shfl_xor(v, 8));
            float mn = fmaxf(mrun[r], v);
            scl[r] = __expf(mrun[r] - mn);
            mrun[r] = mn;
            lrun[r] *= scl[r];
        }
        float p[4][4];
        float rs[4] = {0.f, 0.f, 0.f, 0.f};
        #pragma unroll
        for (int f = 0; f < 4; ++f)
            #pragma unroll
            for (int r = 0; r < 4; ++r) {
                p[f][r] = __expf(sacc[f][r] - mrun[r]);
                rs[r] += p[f][r];
            }
        #pragma unroll
        for (int r = 0; r < 4; ++r) {
            float v = rs[r];
            v += __shfl_xor(v, 1);
            v += __shfl_xor(v, 2);
            v += __shfl_xor(v, 4);
            v += __shfl_xor(v, 8);
            lrun[r] += v;
        }
        // ---- write P into packed frag layout
        #pragma unroll
        for (int f = 0; f < 4; ++f) {
            #pragma unroll
            for (int r = 0; r < 4; ++r) {
                int cl = 16 * w4 + 4 * ls + r;
                int ql = 16 * f + lx;
                int idx = ((cl >> 4) * 2 + (ql >> 5)) * 512 + ((cl & 15) + 16 * ((ql >> 3) & 3)) * 8 + (ql & 7);
                sPp[g][idx] = f2bf(p[f][r]);
            }
        }
        if (lx == 0) {
            #pragma unroll
            for (int r = 0; r < 4; ++r) scaleS[g][16 * w4 + 4 * ls + r] = scl[r];
        }
        __syncthreads();   // sP + scales ready

        // ---- PV: wave owns d-slice [64*w4, +64), all 64 c of its group
        #pragma unroll
        for (int cf = 0; cf < 4; ++cf) {
            #pragma unroll
            for (int r = 0; r < 4; ++r) {
                float s = scaleS[g][16 * cf + 4 * ls + r];
                #pragma unroll
                for (int df = 0; df < 4; ++df) oacc[cf][df][r] *= s;
            }
        }
        bf16x8 pa[2][4];
        #pragma unroll
        for (int kk = 0; kk < 2; ++kk)
            #pragma unroll
            for (int cf = 0; cf < 4; ++cf)
                pa[kk][cf] = *(const bf16x8*)&sPp[g][(cf * 2 + kk) * 512 + l * 8];
        #pragma unroll
        for (int kk = 0; kk < 2; ++kk)
            #pragma unroll
            for (int df = 0; df < 4; ++df)
                #pragma unroll
                for (int cf = 0; cf < 4; ++cf)
                    oacc[cf][df] = __builtin_amdgcn_mfma_f32_16x16x32_bf16(pa[kk][cf], qtb[kk][df], oacc[cf][df], 0, 0, 0);
        __syncthreads();   // PV done; next iter may overwrite sPp
    }

    // ---- in-block merge of the two q-groups
    if (lx == 0) {
        #pragma unroll
        for (int r = 0; r < 4; ++r) {
            mS[g][16 * w4 + 4 * ls + r] = mrun[r];
            lS[g][16 * w4 + 4 * ls + r] = lrun[r];
        }
    }
    __syncthreads();

    float alpha[4][4], ltot[4][4], mtot[4][4];   // [cf][r]
    #pragma unroll
    for (int cf = 0; cf < 4; ++cf) {
        #pragma unroll
        for (int r = 0; r < 4; ++r) {
            int cl = 16 * cf + 4 * ls + r;
            float m0 = mS[0][cl], m1 = mS[1][cl];
            float mx = fmaxf(m0, m1);
            float a0 = __expf(m0 - mx), a1 = __expf(m1 - mx);
            mtot[cf][r] = mx;
            ltot[cf][r] = a0 * lS[0][cl] + a1 * lS[1][cl];
            alpha[cf][r] = (g == 0) ? a0 : a1;
        }
    }
    #pragma unroll
    for (int cf = 0; cf < 4; ++cf) {
        #pragma unroll
        for (int df = 0; df < 4; ++df)
            #pragma unroll
            for (int r = 0; r < 4; ++r)
                oacc[cf][df][r] *= alpha[cf][r];
    }
    #pragma unroll
    for (int cf = 0; cf < 4; ++cf) {
        if (g == 1) {
            #pragma unroll
            for (int df = 0; df < 4; ++df)
                *(f32x4*)&mergebuf[(w4 * 64 + l) * 20 + df * 4] = oacc[cf][df];
        }
        __syncthreads();
        if (g == 0) {
            #pragma unroll
            for (int df = 0; df < 4; ++df) {
                f32x4 v = *(const f32x4*)&mergebuf[(w4 * 64 + l) * 20 + df * 4];
                oacc[cf][df][0] += v[0]; oacc[cf][df][1] += v[1];
                oacc[cf][df][2] += v[2]; oacc[cf][df][3] += v[3];
            }
        }
        __syncthreads();
    }

    if (g == 0) {
        if (wv == 0 && lx == 0) {
            #pragma unroll
            for (int cf = 0; cf < 4; ++cf)
                #pragma unroll
                for (int r = 0; r < 4; ++r) {
                    int cl = 16 * cf + 4 * ls + r;
                    int c = b * LC + c0 + cl;
                    rowmax_out[c] = mtot[cf][r] + ctermS[0][cl] + ctermS[1][cl];
                }
        }
        #pragma unroll
        for (int cf = 0; cf < 4; ++cf) {
            #pragma unroll
            for (int r = 0; r < 4; ++r) {
                float inv = 1.0f / ltot[cf][r];
                size_t row = (size_t)(b * LC + c0 + 16 * cf + 4 * ls + r) * DD;
                #pragma unroll
                for (int df = 0; df < 4; ++df)
                    out[row + 64 * w4 + 16 * df + lx] = oacc[cf][df][r] * inv;
            }
        }
    }
}

__global__ __launch_bounds__(256) void k_q2c(const float* __restrict__ ctx,
                                             const float* __restrict__ rowmax,
                                             float* __restrict__ q2cvec) {
    __shared__ float sm[LC];
    __shared__ float red[256];
    int b = blockIdx.x;
    int chunk = blockIdx.y;
    int t = threadIdx.x;
    const float* rm = rowmax + b * LC;

    float lmax = -1e30f;
    #pragma unroll
    for (int k = 0; k < 4; ++k) {
        float v = rm[t + k * 256];
        sm[t + k * 256] = v;
        lmax = fmaxf(lmax, v);
    }
    red[t] = lmax;
    __syncthreads();
    for (int s = 128; s > 0; s >>= 1) {
        if (t < s) red[t] = fmaxf(red[t], red[t + s]);
        __syncthreads();
    }
    float gmax = red[0];
    __syncthreads();
    float lsum = 0.f;
    #pragma unroll
    for (int k = 0; k < 4; ++k) {
        int i = t + k * 256;
        float e = __expf(sm[i] - gmax);
        sm[i] = e;
        lsum += e;
    }
    red[t] = lsum;
    __syncthreads();
    for (int s = 128; s > 0; s >>= 1) {
        if (t < s) red[t] += red[t + s];
        __syncthreads();
    }
    float inv = 1.0f / red[0];

    int c0 = chunk * 32;
    float acc = 0.f;
    for (int c = c0; c < c0 + 32; ++c)
        acc += sm[c] * ctx[(size_t)(b * LC + c) * DD + t];
    atomicAdd(&q2cvec[b * DD + t], acc * inv);
}

__global__ __launch_bounds__(256) void k_bcast(const float* __restrict__ q2cvec,
                                               float* __restrict__ out2) {
    int g = blockIdx.x * 256 + threadIdx.x;
    int b  = g >> 16;
    int d4 = g & 63;
    ((float4*)out2)[g] = ((const float4*)q2cvec)[b * 64 + d4];
}

extern "C" void kernel_launch(void* const* d_in, const int* in_sizes, int n_in,
                              void* d_out, int out_size, void* d_ws, size_t ws_size,
                              hipStream_t stream) {
    const float* ctx = (const float*)d_in[0];
    const float* qst = (const float*)d_in[1];
    const float* w   = (const float*)d_in[2];
    float* out  = (float*)d_out;
    float* out2 = out + (size_t)BB * LC * DD;   // q2c half; bf16 scratch until k_bcast
    float* ws   = (float*)d_ws;

    float* qterm  = ws;
    float* rowmax = ws + 32768;
    float* q2cvec = ws + 49152;
    short* Qbf  = (short*)out2;
    short* Qtbf = Qbf + (size_t)BB * LQ * DD;

    k_prep<<<dim3(LQ / QTB, BB), 256, 0, stream>>>(qst, w, Qbf, Qtbf, qterm, q2cvec);

    k_main<<<(LC / CTB) * BB, 512, 0, stream>>>(ctx, Qbf, Qtbf, w, ws, out, rowmax);

    k_q2c<<<dim3(BB, 32), 256, 0, stream>>>(ctx, rowmax, q2cvec);

    k_bcast<<<(BB * LC * DD / 4) / 256, 256, 0, stream>>>(q2cvec, out2);
}